// Round 7
// baseline (79.576 us; speedup 1.0000x reference)
//
#include <hip/hip_runtime.h>

typedef unsigned short u16;
typedef unsigned int   u32;

using bf16x8 = __attribute__((ext_vector_type(8))) short;
using f32x4  = __attribute__((ext_vector_type(4))) float;
using u32x4  = __attribute__((ext_vector_type(4))) unsigned;

__device__ __forceinline__ u32 cvtpk(float lo, float hi) {
  u32 r;
  asm("v_cvt_pk_bf16_f32 %0, %1, %2" : "=v"(r) : "v"(lo), "v"(hi));
  return r;
}
__device__ __forceinline__ bf16x8 pack8(float f0,float f1,float f2,float f3,
                                        float f4,float f5,float f6,float f7) {
  u32x4 t; t[0]=cvtpk(f0,f1); t[1]=cvtpk(f2,f3); t[2]=cvtpk(f4,f5); t[3]=cvtpk(f6,f7);
  return __builtin_bit_cast(bf16x8, t);
}
__device__ __forceinline__ u16 f2bf(float f) {
  u32 u = __float_as_uint(f);
  u32 r = u + 0x7FFFu + ((u >> 16) & 1u);
  return (u16)(r >> 16);
}

// ---------------------------------------------------------------------------
// Compile-time level-batched schedule (R4's proven allocator) + phase tables.
// Within a sub-phase: every read's source slot was written in an EARLIER
// sub-phase, and no in-phase write aliases an in-phase read => one-step-ahead
// prefetch inside a phase is race-free by construction.
// ---------------------------------------------------------------------------
struct Sched {
  unsigned v[4][64];        // e:0-5 | slot:6-10 (31=none) | nc:11-12 | s1:13-17 | s2:18-22 | s3:23-27
  unsigned char opi[4][64];
  unsigned char ph_start[4][32];
  unsigned char ph_len[4][32];
  int nph[4];
  int nslot;
  int maxph;
};

constexpr int cCOOR[62][2] = {
  {1,4},{1,5},{1,6},{2,4},{2,6},
  {3,1},{3,2},{3,3},{3,4},{3,5},{3,6},{3,7},{3,8},{3,9},
  {4,1},{4,2},{4,3},{4,4},{4,5},{4,6},{4,7},{4,8},{4,9},
  {5,1},{5,2},{5,3},{5,4},{5,5},{5,6},{5,7},{5,8},{5,9},
  {6,1},{6,2},{6,3},{6,4},{6,5},{6,6},{6,7},{6,8},{6,9},
  {7,1},{7,2},{7,3},{7,4},{7,5},{7,6},{7,7},{7,8},{7,9},
  {8,2},{8,3},{8,4},{8,5},{8,6},{8,7},{8,8},
  {9,3},{9,4},{9,5},{9,6},{9,7}};

constexpr int cDIRS[4][62] = {
  {1,2,3,4,5,6,7,8,9,10,11,12,13,14,15,16,17,18,19,20,21,22,23,24,25,26,27,28,29,30,
   31,32,33,34,35,36,37,38,39,40,41,42,43,44,45,46,47,48,49,50,
   58,52,53,54,55,56,62,60,61,51,57,59},
  {59,57,51,61,60,62,56,55,54,53,52,58,50,41,32,23,14,49,40,31,22,13,48,39,30,21,12,
   47,38,29,20,11,46,37,28,19,10,45,36,27,18,9,44,35,26,17,8,43,34,25,16,7,42,33,24,
   15,6,5,4,3,2,1},
  {59,57,51,61,60,62,56,55,54,53,52,58,50,49,48,47,46,45,44,43,42,41,40,39,38,37,36,
   35,34,33,32,31,30,29,28,27,26,25,24,23,22,21,20,19,18,17,16,15,14,13,12,11,10,9,
   8,7,6,5,4,3,2,1},
  {1,2,3,4,5,6,15,24,33,42,7,16,25,34,43,8,17,26,35,44,9,18,27,36,45,10,19,28,37,46,
   11,20,29,38,47,12,21,30,39,48,13,22,31,40,49,14,23,32,41,50,
   58,52,53,54,55,56,62,60,61,51,57,59}};

constexpr int cOFFS[4][3][2] = {
  {{0,-1},{-1,-1},{-1,0}},
  {{0, 1},{-1, 0},{-1,1}},
  {{0,-1},{ 1,-1},{ 1,0}},
  {{0,-1},{-1,-1},{-1,0}}};

constexpr Sched make_sched() {
  Sched S{};
  int nslot_all = 0, maxph_all = 0;
  for (int d = 0; d < 4; ++d) {
    int pos_of[63] = {};
    for (int p = 0; p < 62; ++p) pos_of[cDIRS[d][p]] = p;
    int nb[62][3] = {}; int nc[62] = {}; int rdcnt[62] = {};
    for (int p = 0; p < 62; ++p) {
      const int e = cDIRS[d][p];
      const int ci = cCOOR[e-1][0], cj = cCOOR[e-1][1];
      for (int o = 0; o < 3; ++o) {
        const int ni = ci + cOFFS[d][o][0], nj = cj + cOFFS[d][o][1];
        int q = 0;
        for (int k2 = 0; k2 < 62; ++k2)
          if (cCOOR[k2][0]==ni && cCOOR[k2][1]==nj) { q = k2+1; break; }
        if (q) { const int qp = pos_of[q];
          if (qp < p) { nb[p][nc[p]] = qp; nc[p] = nc[p]+1; rdcnt[qp] = rdcnt[qp]+1; } }
      }
    }
    int lvl[62] = {};
    for (int p = 0; p < 62; ++p) {
      int m = 0;
      for (int o = 0; o < nc[p]; ++o) if (lvl[nb[p][o]] > m) m = lvl[nb[p][o]];
      lvl[p] = m + 1;
    }
    int ord[62] = {}; int k = 0;
    for (int L = 1; L <= 62; ++L)
      for (int p = 0; p < 62; ++p) if (lvl[p] == L) { ord[k] = p; k = k+1; }
    int slotof[62] = {};
    int rl[20]; int lr[20];
    for (int s = 0; s < 20; ++s) { rl[s] = 0; lr[s] = -1; }
    int nslot = 0, cur_sub = 0;
    int barafter[62] = {};
    int prev_lvl = lvl[ord[0]];
    for (int kk = 0; kk < 62; ++kk) {
      const int p = ord[kk];
      if (lvl[p] != prev_lvl) { barafter[kk-1] = 1; cur_sub = cur_sub+1; prev_lvl = lvl[p]; }
      for (int o = 0; o < nc[p]; ++o) {
        const int s = slotof[nb[p][o]];
        rl[s] = rl[s]-1;
        if (cur_sub > lr[s]) lr[s] = cur_sub;
      }
      int myslot = 31;
      if (rdcnt[p] > 0) {
        int found = -1;
        for (int s = 0; s < nslot; ++s)
          if (rl[s] == 0 && lr[s] < cur_sub) { found = s; break; }
        if (found < 0 && nslot < 19) { found = nslot; nslot = nslot+1; }
        if (found < 0) {
          barafter[kk-1] = 1; cur_sub = cur_sub+1;
          for (int o = 0; o < nc[p]; ++o) {
            const int s = slotof[nb[p][o]];
            if (cur_sub > lr[s]) lr[s] = cur_sub;
          }
          for (int s = 0; s < nslot; ++s)
            if (rl[s] == 0 && lr[s] < cur_sub) { found = s; break; }
        }
        if (found < 0 && nslot < 20) { found = nslot; nslot = nslot+1; }
        if (found < 0) found = 0;
        myslot = found;
        rl[myslot] = rdcnt[p];
        lr[myslot] = -1;
        slotof[p] = myslot;
      }
      S.opi[d][kk] = (unsigned char)p;
      S.v[d][kk] = (unsigned)(cDIRS[d][p]-1)
                 | ((unsigned)myslot << 6)
                 | ((unsigned)nc[p] << 11)
                 | ((unsigned)(nc[p]>0 ? slotof[nb[p][0]] : 0) << 13)
                 | ((unsigned)(nc[p]>1 ? slotof[nb[p][1]] : 0) << 18)
                 | ((unsigned)(nc[p]>2 ? slotof[nb[p][2]] : 0) << 23);
    }
    // phase tables from barafter
    int np = 0, st = 0;
    for (int kk = 0; kk < 62; ++kk) {
      if (barafter[kk] || kk == 61) {
        S.ph_start[d][np] = (unsigned char)st;
        S.ph_len[d][np]   = (unsigned char)(kk - st + 1);
        np = np + 1;
        st = kk + 1;
      }
    }
    S.nph[d] = np;
    if (np > maxph_all) maxph_all = np;
    if (nslot > nslot_all) nslot_all = nslot;
  }
  S.nslot = nslot_all;
  S.maxph = maxph_all;
  return S;
}

constexpr Sched g_sched = make_sched();
static_assert(g_sched.nslot >= 8 && g_sched.nslot <= 20, "slot pressure out of range");
static_assert(g_sched.maxph <= 32, "phase table overflow");
__constant__ Sched c_sched = make_sched();

constexpr int POOL_B    = g_sched.nslot * 4096;
constexpr int SRNN_SMEM = POOL_B + 256;          // + wproj[64] f32

// ---------------------------------------------------------------------------
// SRNN: one WG per (t-pair, d, b-block of 8); 4 waves x 2 n-tiles (R4-proven
// layouts). Phase loop: barrier only at sub-phase ends; within a phase, step
// s+1's A-fragments and x-row are prefetched while step s computes (race-free
// per the allocator invariants above).
// ---------------------------------------------------------------------------
__global__ __launch_bounds__(256, 2) void srnn_kernel(
    const float* __restrict__ x,  const float* __restrict__ Uw,
    const float* __restrict__ Ub, const float* __restrict__ Ww,
    const float* __restrict__ Wb, const float* __restrict__ spbs,
    const float* __restrict__ Pw, const float* __restrict__ psw,
    float* __restrict__ part)
{
  extern __shared__ __align__(16) char smem[];
  const int tid  = threadIdx.x;
  const int lane = tid & 63, wid = tid >> 6;
  const int l15  = lane & 15, lhi = lane >> 4;
  const int bx = blockIdx.x;
  const int bb = bx & 15, d = (bx >> 4) & 3, tp = bx >> 6;
  const int b0 = bb * 8, t0 = tp * 2;

  float* s_wp = (float*)(smem + POOL_B);

  // wproj (schedule order via opi)
  if (tid < 62) {
    const int opi = c_sched.opi[d][tid];
    float acc = 0.f;
    for (int q = 0; q < 16; ++q) acc += Pw[(d * 16 + q) * 62 + opi] * psw[d * 16 + q];
    s_wp[tid] = acc;
  }

  // W B-fragments, k-interleaved (physical q=2i+j <-> logical k=i+16j)
  bf16x8 wf[2][4];
  float bias0, bias1;
#pragma unroll
  for (int nt = 0; nt < 2; ++nt) {
    const int n = wid * 32 + nt * 16 + l15;
    const float* wr = Ww + (size_t)(d * 128 + n) * 128;
#pragma unroll
    for (int kc = 0; kc < 4; ++kc) {
      float4 lo = *(const float4*)(wr + kc * 32 + lhi * 4);
      float4 hi = *(const float4*)(wr + kc * 32 + lhi * 4 + 16);
      wf[nt][kc] = pack8(lo.x, hi.x, lo.y, hi.y, lo.z, hi.z, lo.w, hi.w);
    }
    float bnt = Ub[d * 128 + n] + Wb[d * 128 + n] + spbs[d * 128 + n];
    if (nt == 0) bias0 = bnt; else bias1 = bnt;
  }

  // Uw B-fragments: only lhi==0 lanes carry real k (c=0..4), rest zero.
  float u0a=0,u1a=0,u2a=0,u3a=0,u4a=0, u0b=0,u1b=0,u2b=0,u3b=0,u4b=0;
  if (lhi == 0) {
    const float* ua = Uw + (d * 128 + wid * 32 + l15) * 5;
    const float* ub = Uw + (d * 128 + wid * 32 + 16 + l15) * 5;
    u0a=ua[0]; u1a=ua[1]; u2a=ua[2]; u3a=ua[3]; u4a=ua[4];
    u0b=ub[0]; u1b=ub[1]; u2b=ub[2]; u3b=ub[3]; u4b=ub[4];
  }
  const bf16x8 uwf0 = pack8(u0a,u1a,u2a,u3a,u4a,0.f,0.f,0.f);
  const bf16x8 uwf1 = pack8(u0b,u1b,u2b,u3b,u4b,0.f,0.f,0.f);

  // per-lane LDS byte offsets (R4-proven swizzle pair)
  const int swz_r = ((l15 & 7) << 4);
  u32 rdv[4], wav[4];
#pragma unroll
  for (int kc = 0; kc < 4; ++kc)
    rdv[kc] = (u32)(l15 * 256 + ((kc * 64 + lhi * 16) ^ swz_r));
  const int wcol = wid * 64 + l15 * 4;
#pragma unroll
  for (int r = 0; r < 4; ++r) {
    const int row = lhi * 4 + r;
    wav[r] = (u32)(row * 256 + (wcol ^ ((row & 7) << 4)));
  }

  const float* xlane = x + (size_t)((b0 + (l15 & 7)) * 16 + (t0 + (l15 >> 3))) * 310;
  const unsigned* scv = c_sched.v[d];

  f32x4 macc0 = {0.f,0.f,0.f,0.f}, macc1 = {0.f,0.f,0.f,0.f};

  auto prefetch = [&](unsigned sv, bf16x8 (&A0)[4], bf16x8 (&A1)[4], float (&xv)[5]) {
    const char* p0 = smem + ((sv >> 13) & 31u) * 4096;
    const char* p1 = smem + ((sv >> 18) & 31u) * 4096;
#pragma unroll
    for (int kc = 0; kc < 4; ++kc) {
      A0[kc] = *(const bf16x8*)(p0 + rdv[kc]);
      A1[kc] = *(const bf16x8*)(p1 + rdv[kc]);
    }
    float x0=0,x1=0,x2=0,x3=0,x4=0;
    if (lhi == 0) {
      const float* xp = xlane + (sv & 63u) * 5;
      x0=xp[0]; x1=xp[1]; x2=xp[2]; x3=xp[3]; x4=xp[4];
    }
    xv[0]=x0; xv[1]=x1; xv[2]=x2; xv[3]=x3; xv[4]=x4;
  };

  auto compute = [&](unsigned sv, int kidx,
                     const bf16x8 (&A0)[4], const bf16x8 (&A1)[4], const float (&xv)[5]) {
    const int nbc = (int)((sv >> 11) & 3u);
    bf16x8 C2[4];
    if (nbc > 2) {
      const char* p2 = smem + ((sv >> 23) & 31u) * 4096;
#pragma unroll
      for (int kc = 0; kc < 4; ++kc) C2[kc] = *(const bf16x8*)(p2 + rdv[kc]);
    }
    f32x4 a0 = {bias0, bias0, bias0, bias0};
    f32x4 a1 = {bias1, bias1, bias1, bias1};
    if (nbc > 0) {
#pragma unroll
      for (int kc = 0; kc < 4; ++kc) {
        a0 = __builtin_amdgcn_mfma_f32_16x16x32_bf16(A0[kc], wf[0][kc], a0, 0, 0, 0);
        a1 = __builtin_amdgcn_mfma_f32_16x16x32_bf16(A0[kc], wf[1][kc], a1, 0, 0, 0);
      }
    }
    if (nbc > 1) {
#pragma unroll
      for (int kc = 0; kc < 4; ++kc) {
        a0 = __builtin_amdgcn_mfma_f32_16x16x32_bf16(A1[kc], wf[0][kc], a0, 0, 0, 0);
        a1 = __builtin_amdgcn_mfma_f32_16x16x32_bf16(A1[kc], wf[1][kc], a1, 0, 0, 0);
      }
    }
    if (nbc > 2) {
#pragma unroll
      for (int kc = 0; kc < 4; ++kc) {
        a0 = __builtin_amdgcn_mfma_f32_16x16x32_bf16(C2[kc], wf[0][kc], a0, 0, 0, 0);
        a1 = __builtin_amdgcn_mfma_f32_16x16x32_bf16(C2[kc], wf[1][kc], a1, 0, 0, 0);
      }
    }
    bf16x8 xa = pack8(xv[0], xv[1], xv[2], xv[3], xv[4], 0.f, 0.f, 0.f);
    a0 = __builtin_amdgcn_mfma_f32_16x16x32_bf16(xa, uwf0, a0, 0, 0, 0);
    a1 = __builtin_amdgcn_mfma_f32_16x16x32_bf16(xa, uwf1, a1, 0, 0, 0);

    const int snew = (int)((sv >> 6) & 31u);
    const float wp = s_wp[kidx];
    float h0r[4], h1r[4];
#pragma unroll
    for (int r = 0; r < 4; ++r) { h0r[r] = fmaxf(a0[r], 0.f); h1r[r] = fmaxf(a1[r], 0.f); }
    if (snew != 31) {
      char* dst = smem + snew * 4096;
#pragma unroll
      for (int r = 0; r < 4; ++r)
        *(u32*)(dst + wav[r]) = cvtpk(h0r[r], h1r[r]);
    }
#pragma unroll
    for (int r = 0; r < 4; ++r) { macc0[r] += h0r[r] * wp; macc1[r] += h1r[r] * wp; }
  };

  __syncthreads();   // s_wp + (slots start garbage; level-1 steps read nothing)

  bf16x8 PA[4], PB[4], QA[4], QB[4];
  float pxv[5], qxv[5];

  const int nph = c_sched.nph[d];
  int s = 0;
  for (int ph = 0; ph < nph; ++ph) {
    int rem = (int)c_sched.ph_len[d][ph];
    prefetch(scv[s], PA, PB, pxv);
    while (rem >= 2) {
      prefetch(scv[s + 1], QA, QB, qxv);
      compute(scv[s], s, PA, PB, pxv);
      ++s; --rem;
      if (rem >= 2) {
        prefetch(scv[s + 1], PA, PB, pxv);
        compute(scv[s], s, QA, QB, qxv);
        ++s; --rem;
      } else {
        compute(scv[s], s, QA, QB, qxv);
        ++s; --rem;
      }
    }
    if (rem == 1) { compute(scv[s], s, PA, PB, pxv); ++s; }
    __syncthreads();
  }

  // ---- store per-(d,t) partial of m ------------------------------------------
#pragma unroll
  for (int r = 0; r < 4; ++r) {
    const int row = lhi * 4 + r;
    const int t = t0 + (row >> 3);
    const int brow = b0 + (row & 7);
    const int n0 = wid * 32 + l15;
    float* pp = part + (((size_t)d * 16 + t) * 128 + brow) * 128;
    pp[n0]      = macc0[r];
    pp[n0 + 16] = macc1[r];
  }
}

// ---------------------------------------------------------------------------
// Reduce 4 direction-partials + C0 -> ms (bf16). Block 0 zeroes d_out.
// ---------------------------------------------------------------------------
__global__ __launch_bounds__(256) void reduce_ms_kernel(
    const float* __restrict__ part, const float* __restrict__ Pb,
    const float* __restrict__ psw,  const float* __restrict__ psb,
    u16* __restrict__ msbf, float* __restrict__ out)
{
  const int tid = threadIdx.x;
  if (blockIdx.x == 0 && tid < 128) {
    float3 z = {0.f, 0.f, 0.f};
    *(float3*)(out + tid * 3) = z;
  }
  const int idx = blockIdx.x * 256 + tid;   // 262144 total
  float c0 = psb[0];
  for (int i = 0; i < 64; ++i) c0 += Pb[i] * psw[i];
  float s = c0 + part[idx] + part[262144 + idx] + part[2 * 262144 + idx] + part[3 * 262144 + idx];
  msbf[idx] = f2bf(s);
}

// ---------------------------------------------------------------------------
// TRNN (R5-verified): 16 WGs = 8 b-blocks x 2 dirs. ms (bf16) -> swizzled LDS;
// 16-step barrier'd scan; in-register p1-dot reduction; atomicAdd into out.
// ---------------------------------------------------------------------------
constexpr int MS_OFF = 0;                 // [16 t][16 b][256 B] swizzled bf16
constexpr int HB_OFF = 65536;             // hbuf [2][16][136] u16 = 8704
constexpr int SW_OFF = HB_OFF + 8704;     // sredw [16][16][4] f32 = 4096
constexpr int S2_OFF = SW_OFF + 4096;     // sred2 [16][16] f32 = 1024
constexpr int TRNN_SMEM = S2_OFF + 1024;  // 79360

__global__ __launch_bounds__(256) void trnn_kernel(
    const u16* __restrict__ msbf,
    const float* __restrict__ frs, const float* __restrict__ frsb,
    const float* __restrict__ fvs, const float* __restrict__ fvsb,
    const float* __restrict__ fbs, const float* __restrict__ fpj, const float* __restrict__ fpjb,
    const float* __restrict__ brs, const float* __restrict__ brsb,
    const float* __restrict__ bvs, const float* __restrict__ bvsb,
    const float* __restrict__ bbs, const float* __restrict__ bpj, const float* __restrict__ bpjb,
    const float* __restrict__ fp1w, const float* __restrict__ fp1b,
    const float* __restrict__ fp2w, const float* __restrict__ fp2b,
    const float* __restrict__ bp1w, const float* __restrict__ bp1b,
    const float* __restrict__ bp2w, const float* __restrict__ bp2b,
    float* __restrict__ out)
{
  extern __shared__ __align__(16) char smem[];
  const int tid = threadIdx.x;
  const int lane = tid & 63, wid = tid >> 6;
  const int l15 = lane & 15, lhi = lane >> 4;
  const int dir = blockIdx.x & 1;
  const int b0 = (blockIdx.x >> 1) * 16;

  const float* rs  = dir ? brs  : frs;
  const float* rsb = dir ? brsb : frsb;
  const float* vs  = dir ? bvs  : fvs;
  const float* vsb = dir ? bvsb : fvsb;
  const float* bs  = dir ? bbs  : fbs;
  const float* w1  = dir ? bp1w : fp1w;

  // ---- prologue A: ms slice (bf16) -> LDS swizzled ---------------------------
  {
    const int tq = tid >> 4, bq = tid & 15;
    const u16* mg = msbf + ((size_t)tq * 128 + b0 + bq) * 128;
    char* mrow = smem + MS_OFF + (tq * 16 + bq) * 256;
    const int sz = (bq & 7) << 4;
#pragma unroll
    for (int q = 0; q < 16; ++q) {
      uint4 v = *(const uint4*)(mg + q * 8);
      *(u32*)(mrow + ((q * 16)      ^ sz)) = v.x;
      *(u32*)(mrow + ((q * 16 + 4)  ^ sz)) = v.y;
      *(u32*)(mrow + ((q * 16 + 8)  ^ sz)) = v.z;
      *(u32*)(mrow + ((q * 16 + 12) ^ sz)) = v.w;
    }
  }

  // ---- prologue B: weight fragments ------------------------------------------
  bf16x8 rf[2][4], vf[2][4];
  float bias[2], w1a, w1b;
#pragma unroll
  for (int nt = 0; nt < 2; ++nt) {
    const int n = wid * 32 + nt * 16 + l15;
#pragma unroll
    for (int kc = 0; kc < 4; ++kc) {
      float4 ra = *(const float4*)(rs + (size_t)n * 128 + kc * 32 + lhi * 8);
      float4 rb = *(const float4*)(rs + (size_t)n * 128 + kc * 32 + lhi * 8 + 4);
      rf[nt][kc] = pack8(ra.x, ra.y, ra.z, ra.w, rb.x, rb.y, rb.z, rb.w);
      float4 lo = *(const float4*)(vs + (size_t)n * 128 + kc * 32 + lhi * 4);
      float4 hi = *(const float4*)(vs + (size_t)n * 128 + kc * 32 + lhi * 4 + 16);
      vf[nt][kc] = pack8(lo.x, hi.x, lo.y, hi.y, lo.z, hi.z, lo.w, hi.w);
    }
    bias[nt] = rsb[n] + vsb[n] + bs[n];
  }
  w1a = w1[wid * 32 + l15];
  w1b = w1[wid * 32 + 16 + l15];

  for (int i = tid; i < 2176; i += 256) *(u16*)(smem + HB_OFF + i * 2) = 0;
  __syncthreads();

  float* sredw = (float*)(smem + SW_OFF);
  float* sred2 = (float*)(smem + S2_OFF);

  int cur = 0;
  for (int tt2 = 0; tt2 < 16; ++tt2) {
    const int tt = dir ? (15 - tt2) : tt2;
    f32x4 am0 = {bias[0],bias[0],bias[0],bias[0]};
    f32x4 am1 = {bias[1],bias[1],bias[1],bias[1]};
    f32x4 ah0 = {0.f,0.f,0.f,0.f}, ah1 = {0.f,0.f,0.f,0.f};
    const char* msrow = smem + MS_OFF + (tt * 16 + l15) * 256;
    const int msz = (l15 & 7) << 4;
#pragma unroll
    for (int kc = 0; kc < 4; ++kc) {
      bf16x8 ma = *(const bf16x8*)(msrow + ((kc * 64 + lhi * 16) ^ msz));
      bf16x8 ha = *(const bf16x8*)(smem + HB_OFF + (cur * 16 + l15) * 272 + kc * 64 + lhi * 16);
      am0 = __builtin_amdgcn_mfma_f32_16x16x32_bf16(ma, rf[0][kc], am0, 0, 0, 0);
      ah0 = __builtin_amdgcn_mfma_f32_16x16x32_bf16(ha, vf[0][kc], ah0, 0, 0, 0);
      am1 = __builtin_amdgcn_mfma_f32_16x16x32_bf16(ma, rf[1][kc], am1, 0, 0, 0);
      ah1 = __builtin_amdgcn_mfma_f32_16x16x32_bf16(ha, vf[1][kc], ah1, 0, 0, 0);
    }
    float pr[4];
#pragma unroll
    for (int r = 0; r < 4; ++r) {
      const int row = lhi * 4 + r;
      float h0 = fmaxf(am0[r] + ah0[r], 0.f);
      float h1 = fmaxf(am1[r] + ah1[r], 0.f);
      *(u32*)(smem + HB_OFF + ((cur ^ 1) * 16 + row) * 272 + wid * 64 + l15 * 4) = cvtpk(h0, h1);
      pr[r] = h0 * w1a + h1 * w1b;
    }
#pragma unroll
    for (int r = 0; r < 4; ++r) {
      float p = pr[r];
      p += __shfl_xor(p, 1);
      p += __shfl_xor(p, 2);
      p += __shfl_xor(p, 4);
      p += __shfl_xor(p, 8);
      if (l15 == 0) sredw[(tt2 * 16 + lhi * 4 + r) * 4 + wid] = p;
    }
    __syncthreads();
    cur ^= 1;
  }

  {
    const int tq = tid >> 4, bq = tid & 15;
    const float* sw = sredw + (tq * 16 + bq) * 4;
    sred2[tq * 16 + bq] = sw[0] + sw[1] + sw[2] + sw[3];
  }
  __syncthreads();

  if (tid < 48) {
    const int b = tid / 3, c = tid % 3;
    const float* p1w = dir ? bp1w : fp1w;
    const float* p1b = dir ? bp1b : fp1b;
    const float* p2w = dir ? bp2w : fp2w;
    const float* p2b = dir ? bp2b : fp2b;
    const float* pj  = dir ? bpj  : fpj;
    const float* pjb = dir ? bpjb : fpjb;
    float S1 = 0.f;
    for (int h = 0; h < 128; ++h) S1 += p1w[h];
    float val = p2b[c];
    for (int p = 0; p < 8; ++p) val += (pjb[p] * S1 + p1b[0]) * p2w[c * 8 + p];
    for (int t2 = 0; t2 < 16; ++t2) {
      float g = 0.f;
      for (int p = 0; p < 8; ++p) g += p2w[c * 8 + p] * pj[p * 16 + t2];
      val += sred2[t2 * 16 + b] * g;
    }
    atomicAdd(out + (b0 + b) * 3 + c, val);
  }
}

extern "C" void kernel_launch(void* const* d_in, const int* in_sizes, int n_in,
                              void* d_out, int out_size, void* d_ws, size_t ws_size,
                              hipStream_t stream)
{
  (void)in_sizes; (void)n_in; (void)out_size; (void)ws_size;
  const float* x    = (const float*)d_in[0];
  const float* Uw   = (const float*)d_in[3];
  const float* Ub   = (const float*)d_in[4];
  const float* Ww   = (const float*)d_in[5];
  const float* Wb   = (const float*)d_in[6];
  const float* spbs = (const float*)d_in[7];
  const float* Pw   = (const float*)d_in[8];
  const float* Pb   = (const float*)d_in[9];
  const float* psw  = (const float*)d_in[10];
  const float* psb  = (const float*)d_in[11];
  const float* frs  = (const float*)d_in[12];
  const float* frsb = (const float*)d_in[13];
  const float* fvs  = (const float*)d_in[14];
  const float* fvsb = (const float*)d_in[15];
  const float* fbs  = (const float*)d_in[16];
  const float* fpj  = (const float*)d_in[17];
  const float* fpjb = (const float*)d_in[18];
  const float* brs  = (const float*)d_in[19];
  const float* brsb = (const float*)d_in[20];
  const float* bvs  = (const float*)d_in[21];
  const float* bvsb = (const float*)d_in[22];
  const float* bbs  = (const float*)d_in[23];
  const float* bpj  = (const float*)d_in[24];
  const float* bpjb = (const float*)d_in[25];
  const float* fp1w = (const float*)d_in[26];
  const float* fp1b = (const float*)d_in[27];
  const float* fp2w = (const float*)d_in[28];
  const float* fp2b = (const float*)d_in[29];
  const float* bp1w = (const float*)d_in[30];
  const float* bp1b = (const float*)d_in[31];
  const float* bp2w = (const float*)d_in[32];
  const float* bp2b = (const float*)d_in[33];

  char* ws = (char*)d_ws;
  float* part = (float*)ws;                 // 4 MiB [4][16][128][128] f32
  u16*   msbf = (u16*)(ws + 4194304);       // 512 KiB [16][128][128] bf16

  hipFuncSetAttribute((const void*)srnn_kernel,
                      hipFuncAttributeMaxDynamicSharedMemorySize, SRNN_SMEM);
  hipFuncSetAttribute((const void*)trnn_kernel,
                      hipFuncAttributeMaxDynamicSharedMemorySize, TRNN_SMEM);

  srnn_kernel<<<dim3(512), dim3(256), SRNN_SMEM, stream>>>(
      x, Uw, Ub, Ww, Wb, spbs, Pw, psw, part);
  reduce_ms_kernel<<<dim3(1024), dim3(256), 0, stream>>>(
      part, Pb, psw, psb, msbf, (float*)d_out);
  trnn_kernel<<<dim3(16), dim3(256), TRNN_SMEM, stream>>>(msbf,
      frs, frsb, fvs, fvsb, fbs, fpj, fpjb,
      brs, brsb, bvs, bvsb, bbs, bpj, bpjb,
      fp1w, fp1b, fp2w, fp2b, bp1w, bp1b, bp2w, bp2b,
      (float*)d_out);
}